// Round 1
// baseline (5102.354 us; speedup 1.0000x reference)
//
#include <hip/hip_runtime.h>
#include <hip/hip_bf16.h>
#include <math.h>

// Nystrom attention, fp32 correctness-first implementation.
// Pipeline: stable counting sort -> QKV GEMM (gathered) -> landmarks ->
// a2 softmax -> pinv (Newton-Schulz, 4 GEMMs/iter) -> t1 (flash a3@v) ->
// t2 = z@t1 -> fused a1@t2 + depthwise conv33 -> output projection + scatter.

#define N_TOK   16384
#define DIMF    512
#define HEADS   8
#define DH      64
#define NCLUST  512
#define QKV_COLS 1536
#define PINV_IT 6
#define KW      33
#define KPAD    16

// ---------------- sort ----------------
__global__ void k_hist(const int* __restrict__ labels, int* __restrict__ counts) {
  int i = blockIdx.x * blockDim.x + threadIdx.x;
  if (i < N_TOK) atomicAdd(&counts[labels[i]], 1);
}

__global__ void k_scan(const int* __restrict__ counts, int* __restrict__ offsets) {
  __shared__ int s[NCLUST];
  int t = threadIdx.x;
  s[t] = counts[t];
  __syncthreads();
  for (int off = 1; off < NCLUST; off <<= 1) {
    int v = (t >= off) ? s[t - off] : 0;
    __syncthreads();
    s[t] += v;
    __syncthreads();
  }
  offsets[t] = s[t] - counts[t];  // exclusive
}

// one wave per cluster; in-order ballot scan reproduces stable argsort
__global__ void k_build_idx(const int* __restrict__ labels, const int* __restrict__ offsets,
                            int* __restrict__ idx) {
  int c = blockIdx.x;
  int lane = threadIdx.x;  // 64
  int base = offsets[c];
  for (int j0 = 0; j0 < N_TOK; j0 += 64) {
    int lbl = labels[j0 + lane];
    unsigned long long mask = __ballot(lbl == c);
    if (lbl == c) {
      int pos = base + (int)__popcll(mask & ((1ULL << lane) - 1ULL));
      idx[pos] = j0 + lane;
    }
    base += (int)__popcll(mask);
  }
}

// ---------------- QKV GEMM with row gather ----------------
__global__ __launch_bounds__(256)
void k_qkv(const float* __restrict__ x, const float* __restrict__ wqkv,
           const int* __restrict__ idx,
           float* __restrict__ q, float* __restrict__ k, float* __restrict__ v) {
  __shared__ float As[16][65];
  __shared__ float Bs[16][65];
  __shared__ int rowIdx[64];
  int tid = threadIdx.x;
  int p0 = blockIdx.y * 64;
  int j0 = blockIdx.x * 64;
  if (tid < 64) rowIdx[tid] = idx[p0 + tid];
  __syncthreads();
  int ty = tid >> 4, tx = tid & 15;
  float acc[4][4] = {};
  for (int k0 = 0; k0 < DIMF; k0 += 16) {
#pragma unroll
    for (int l = 0; l < 4; ++l) {
      int lin = tid + l * 256;
      int row = lin >> 4, kk = lin & 15;
      As[kk][row] = x[(size_t)rowIdx[row] * DIMF + k0 + kk];
      Bs[kk][row] = wqkv[(size_t)(j0 + row) * DIMF + k0 + kk];
    }
    __syncthreads();
#pragma unroll
    for (int kk = 0; kk < 16; ++kk) {
      float a[4], b[4];
#pragma unroll
      for (int i = 0; i < 4; ++i) a[i] = As[kk][ty * 4 + i];
#pragma unroll
      for (int j = 0; j < 4; ++j) b[j] = Bs[kk][tx * 4 + j];
#pragma unroll
      for (int i = 0; i < 4; ++i)
#pragma unroll
        for (int j = 0; j < 4; ++j) acc[i][j] += a[i] * b[j];
    }
    __syncthreads();
  }
  int which = j0 >> 9;            // 0=q 1=k 2=v  (block spans one 64-col slab)
  int h = (j0 >> 6) & 7;
  float* dst = (which == 0) ? q : (which == 1) ? k : v;
#pragma unroll
  for (int i = 0; i < 4; ++i) {
    int p = p0 + ty * 4 + i;
    float4 val = make_float4(acc[i][0], acc[i][1], acc[i][2], acc[i][3]);
    *(float4*)&dst[(((size_t)h * N_TOK) + p) * DH + tx * 4] = val;
  }
}

// ---------------- landmarks (segment means over sorted ranges) ----------------
__global__ void k_landmarks(const float* __restrict__ q, const float* __restrict__ k,
                            const int* __restrict__ offsets, const int* __restrict__ counts,
                            float* __restrict__ ql, float* __restrict__ kl) {
  int c = blockIdx.x, h = blockIdx.y, d = threadIdx.x;
  int off = offsets[c], cnt = counts[c];
  const float* qp = q + ((size_t)h * N_TOK) * DH + d;
  const float* kp = k + ((size_t)h * N_TOK) * DH + d;
  float sq = 0.f, sk = 0.f;
  for (int i = 0; i < cnt; ++i) {
    sq += qp[(size_t)(off + i) * DH];
    sk += kp[(size_t)(off + i) * DH];
  }
  float inv = 1.f / (float)(cnt > 0 ? cnt : 1);
  ql[(((size_t)h * NCLUST) + c) * DH + d] = sq * inv;
  kl[(((size_t)h * NCLUST) + c) * DH + d] = sk * inv;
}

// ---------------- a2 = softmax(q_l @ k_l^T) rows ----------------
__global__ __launch_bounds__(256)
void k_a2(const float* __restrict__ ql, const float* __restrict__ kl, float* __restrict__ a2) {
  int r = blockIdx.x, h = blockIdx.y, t = threadIdx.x;
  __shared__ float qrow[DH];
  __shared__ float red[256];
  if (t < DH) qrow[t] = ql[(((size_t)h * NCLUST) + r) * DH + t];
  __syncthreads();
  const float* klh = kl + (size_t)h * NCLUST * DH;
  float s0 = 0, s1 = 0;
  for (int d = 0; d < DH; ++d) {
    float qd = qrow[d];
    s0 += qd * klh[(size_t)t * DH + d];
    s1 += qd * klh[(size_t)(t + 256) * DH + d];
  }
  red[t] = fmaxf(s0, s1);
  __syncthreads();
  for (int o = 128; o > 0; o >>= 1) { if (t < o) red[t] = fmaxf(red[t], red[t + o]); __syncthreads(); }
  float m = red[0];
  __syncthreads();
  float e0 = __expf(s0 - m), e1 = __expf(s1 - m);
  red[t] = e0 + e1;
  __syncthreads();
  for (int o = 128; o > 0; o >>= 1) { if (t < o) red[t] += red[t + o]; __syncthreads(); }
  float inv = 1.f / red[0];
  float* row = a2 + (((size_t)h * NCLUST) + r) * NCLUST;
  row[t] = e0 * inv;
  row[t + 256] = e1 * inv;
}

// ---------------- pinv init: global max col/row sums ----------------
__global__ void k_colrow_max(const float* __restrict__ a2, unsigned* __restrict__ maxes) {
  int h = blockIdx.y;
  int c = blockIdx.x * 64 + threadIdx.x;
  const float* A = a2 + (size_t)h * NCLUST * NCLUST;
  float s = 0;
  for (int r = 0; r < NCLUST; ++r) s += A[(size_t)r * NCLUST + c];
  atomicMax(&maxes[0], __float_as_uint(s));
  float rs = 0;
  for (int j = 0; j < NCLUST; ++j) rs += A[(size_t)c * NCLUST + j];
  atomicMax(&maxes[1], __float_as_uint(rs));
}

__global__ __launch_bounds__(256)
void k_z0(const float* __restrict__ a2, const unsigned* __restrict__ maxes, float* __restrict__ z) {
  __shared__ float s[32][33];
  int h = blockIdx.z;
  int i0 = blockIdx.x * 32, j0 = blockIdx.y * 32;
  float inv = 1.f / (__uint_as_float(maxes[0]) * __uint_as_float(maxes[1]));
  const float* A = a2 + (size_t)h * NCLUST * NCLUST;
  float* Z = z + (size_t)h * NCLUST * NCLUST;
  int t = threadIdx.x;
#pragma unroll
  for (int l = 0; l < 4; ++l) {
    int lin = t + l * 256;
    int a = lin >> 5, b = lin & 31;
    s[a][b] = A[(size_t)(j0 + a) * NCLUST + i0 + b];
  }
  __syncthreads();
#pragma unroll
  for (int l = 0; l < 4; ++l) {
    int lin = t + l * 256;
    int a = lin >> 5, b = lin & 31;
    Z[(size_t)(i0 + a) * NCLUST + j0 + b] = s[b][a] * inv;
  }
}

// ---------------- batched 512x512 GEMM: C = scale*(alpha*A - A@B) ----------------
__global__ __launch_bounds__(256)
void k_gemm512(const float* __restrict__ A, const float* __restrict__ B, float* __restrict__ C,
               float alpha, float scale) {
  __shared__ float As[16][65];
  __shared__ float Bs[16][65];
  int h = blockIdx.z;
  const float* Ah = A + (size_t)h * NCLUST * NCLUST;
  const float* Bh = B + (size_t)h * NCLUST * NCLUST;
  float* Ch = C + (size_t)h * NCLUST * NCLUST;
  int tid = threadIdx.x;
  int m0 = blockIdx.y * 64, n0 = blockIdx.x * 64;
  int ty = tid >> 4, tx = tid & 15;
  float acc[4][4] = {};
  for (int k0 = 0; k0 < NCLUST; k0 += 16) {
#pragma unroll
    for (int l = 0; l < 4; ++l) {
      int lin = tid + l * 256;
      int rowA = lin >> 4, kkA = lin & 15;     // A: k contiguous
      As[kkA][rowA] = Ah[(size_t)(m0 + rowA) * NCLUST + k0 + kkA];
      int nB = lin & 63, kkB = lin >> 6;       // B: n contiguous
      Bs[kkB][nB] = Bh[(size_t)(k0 + kkB) * NCLUST + n0 + nB];
    }
    __syncthreads();
#pragma unroll
    for (int kk = 0; kk < 16; ++kk) {
      float a[4], b[4];
#pragma unroll
      for (int i = 0; i < 4; ++i) a[i] = As[kk][ty * 4 + i];
#pragma unroll
      for (int j = 0; j < 4; ++j) b[j] = Bs[kk][tx * 4 + j];
#pragma unroll
      for (int i = 0; i < 4; ++i)
#pragma unroll
        for (int j = 0; j < 4; ++j) acc[i][j] += a[i] * b[j];
    }
    __syncthreads();
  }
#pragma unroll
  for (int i = 0; i < 4; ++i) {
    int m = m0 + ty * 4 + i;
    float4 av = make_float4(0.f, 0.f, 0.f, 0.f);
    if (alpha != 0.f) av = *(const float4*)&Ah[(size_t)m * NCLUST + n0 + tx * 4];
    float4 o;
    o.x = scale * (alpha * av.x - acc[i][0]);
    o.y = scale * (alpha * av.y - acc[i][1]);
    o.z = scale * (alpha * av.z - acc[i][2]);
    o.w = scale * (alpha * av.w - acc[i][3]);
    *(float4*)&Ch[(size_t)m * NCLUST + n0 + tx * 4] = o;
  }
}

// ---------------- t1 = softmax(q_l@k^T) @ v  (flash, 16 q-rows/block) ----------------
__global__ __launch_bounds__(256)
void k_t1(const float* __restrict__ ql, const float* __restrict__ k, const float* __restrict__ v,
          float* __restrict__ t1) {
  __shared__ float qs[16][68];
  __shared__ float ks[64][68];
  __shared__ float vs[64][68];
  __shared__ float P[16][68];
  __shared__ float red[16][17];
  __shared__ float mrun[16], srun[16], fs[16];
  int h = blockIdx.y;
  int r0 = blockIdx.x * 16;
  int t = threadIdx.x;
#pragma unroll
  for (int l = 0; l < 4; ++l) {
    int lin = t + l * 256;  // 1024 = 16*64
    int r = lin >> 6, d = lin & 63;
    qs[r][d] = ql[(((size_t)h * NCLUST) + r0 + r) * DH + d];
  }
  if (t < 16) { mrun[t] = -1e30f; srun[t] = 0.f; }
  float acc0 = 0, acc1 = 0, acc2 = 0, acc3 = 0;
  int rr = t & 15;
  int jg = t >> 4;  // 0..15
  const float* kh = k + (size_t)h * N_TOK * DH;
  const float* vh = v + (size_t)h * N_TOK * DH;
  __syncthreads();
  for (int j0 = 0; j0 < N_TOK; j0 += 64) {
#pragma unroll
    for (int l = 0; l < 16; ++l) {
      int lin = t + l * 256;  // 4096 = 64*64
      int j = lin >> 6, d = lin & 63;
      ks[j][d] = kh[(size_t)(j0 + j) * DH + d];
      vs[j][d] = vh[(size_t)(j0 + j) * DH + d];
    }
    __syncthreads();
    // dots
    float sv[4];
#pragma unroll
    for (int jj = 0; jj < 4; ++jj) {
      int j = jg * 4 + jj;
      const float4* qv = (const float4*)&qs[rr][0];
      const float4* kv = (const float4*)&ks[j][0];
      float s = 0;
#pragma unroll
      for (int d4 = 0; d4 < 16; ++d4) {
        float4 a = qv[d4], b = kv[d4];
        s += a.x * b.x + a.y * b.y + a.z * b.z + a.w * b.w;
      }
      sv[jj] = s;
    }
    red[rr][jg] = fmaxf(fmaxf(sv[0], sv[1]), fmaxf(sv[2], sv[3]));
    __syncthreads();
    if (t < 16) {
      float cm = red[t][0];
      for (int g = 1; g < 16; ++g) cm = fmaxf(cm, red[t][g]);
      float mo = mrun[t];
      float mn = fmaxf(mo, cm);
      float f = __expf(mo - mn);
      mrun[t] = mn; fs[t] = f; srun[t] *= f;
    }
    __syncthreads();
    float mn = mrun[rr];
    float ls = 0;
#pragma unroll
    for (int jj = 0; jj < 4; ++jj) {
      float e = __expf(sv[jj] - mn);
      P[rr][jg * 4 + jj] = e;
      ls += e;
    }
    red[rr][jg] = ls;
    __syncthreads();
    if (t < 16) {
      float cs = 0;
      for (int g = 0; g < 16; ++g) cs += red[t][g];
      srun[t] += cs;
    }
    // PV with rescale; (rr, dg=jg) owns 4 d's
    float f = fs[rr];
    int dbase = jg * 4;
    float a0 = acc0 * f, a1 = acc1 * f, a2v = acc2 * f, a3v = acc3 * f;
#pragma unroll 8
    for (int j = 0; j < 64; ++j) {
      float p = P[rr][j];
      const float* vrow = &vs[j][dbase];
      a0 += p * vrow[0]; a1 += p * vrow[1]; a2v += p * vrow[2]; a3v += p * vrow[3];
    }
    acc0 = a0; acc1 = a1; acc2 = a2v; acc3 = a3v;
    __syncthreads();
  }
  float inv = 1.f / srun[rr];
  float* outp = &t1[(((size_t)h * NCLUST) + r0 + rr) * DH + jg * 4];
  outp[0] = acc0 * inv; outp[1] = acc1 * inv; outp[2] = acc2 * inv; outp[3] = acc3 * inv;
}

// ---------------- t2 = z @ t1 ----------------
__global__ void k_t2(const float* __restrict__ z, const float* __restrict__ t1, float* __restrict__ t2) {
  int r = blockIdx.x, h = blockIdx.y, d = threadIdx.x;
  const float* zr = z + (((size_t)h * NCLUST) + r) * NCLUST;
  const float* t1h = t1 + (size_t)h * NCLUST * DH;
  float s = 0;
  for (int c = 0; c < NCLUST; ++c) s += zr[c] * t1h[(size_t)c * DH + d];
  t2[(((size_t)h * NCLUST) + r) * DH + d] = s;
}

// ---------------- out = softmax(q@k_l^T)@t2 + conv33(v), 32 rows/block ----------------
__global__ __launch_bounds__(256)
void k_out_attn(const float* __restrict__ q, const float* __restrict__ kl,
                const float* __restrict__ t2, const float* __restrict__ v,
                const float* __restrict__ wres, float* __restrict__ ao) {
  __shared__ float qs[32][68];
  __shared__ float ks[64][68];
  __shared__ float S[32][513];
  __shared__ float sums[32];
  __shared__ float wr[KW];
  int h = blockIdx.y;
  int p0 = blockIdx.x * 32;
  int t = threadIdx.x;
  const float* qh = q + (size_t)h * N_TOK * DH;
  const float* klh = kl + (size_t)h * NCLUST * DH;
  const float* t2h = t2 + (size_t)h * NCLUST * DH;
  const float* vh = v + (size_t)h * N_TOK * DH;
  if (t < KW) wr[t] = wres[h * KW + t];
#pragma unroll
  for (int l = 0; l < 8; ++l) {
    int lin = t + l * 256;  // 2048 = 32*64
    int r = lin >> 6, d = lin & 63;
    qs[r][d] = qh[(size_t)(p0 + r) * DH + d];
  }
  __syncthreads();
  int rr = t & 31, cg = t >> 5;  // cg 0..7
  for (int c0 = 0; c0 < NCLUST; c0 += 64) {
#pragma unroll
    for (int l = 0; l < 16; ++l) {
      int lin = t + l * 256;
      int j = lin >> 6, d = lin & 63;
      ks[j][d] = klh[(size_t)(c0 + j) * DH + d];
    }
    __syncthreads();
#pragma unroll
    for (int cc = 0; cc < 8; ++cc) {
      int j = cg * 8 + cc;
      const float4* qv = (const float4*)&qs[rr][0];
      const float4* kv = (const float4*)&ks[j][0];
      float s = 0;
#pragma unroll
      for (int d4 = 0; d4 < 16; ++d4) {
        float4 a = qv[d4], b = kv[d4];
        s += a.x * b.x + a.y * b.y + a.z * b.z + a.w * b.w;
      }
      S[rr][c0 + j] = s;
    }
    __syncthreads();
  }
  // row softmax (4 waves x 8 rows)
  int wave = t >> 6, lane = t & 63;
  for (int r = wave; r < 32; r += 4) {
    float m = -1e30f;
    for (int c = lane; c < NCLUST; c += 64) m = fmaxf(m, S[r][c]);
    for (int o = 32; o > 0; o >>= 1) m = fmaxf(m, __shfl_xor(m, o, 64));
    float s = 0;
    for (int c = lane; c < NCLUST; c += 64) {
      float e = __expf(S[r][c] - m);
      S[r][c] = e;
      s += e;
    }
    for (int o = 32; o > 0; o >>= 1) s += __shfl_xor(s, o, 64);
    if (lane == 0) sums[r] = s;
  }
  __syncthreads();
  // PV + conv residual; (rr, dg) owns 8 d's
  int dg = t >> 5;
  int dbase = dg * 8;
  float acc[8] = {};
  for (int c = 0; c < NCLUST; ++c) {
    float p = S[rr][c];
    const float* t2r = &t2h[(size_t)c * DH + dbase];
#pragma unroll
    for (int u = 0; u < 8; ++u) acc[u] += p * t2r[u];
  }
  float inv = 1.f / sums[rr];
#pragma unroll
  for (int u = 0; u < 8; ++u) acc[u] *= inv;
  int prow = p0 + rr;
  for (int tt = 0; tt < KW; ++tt) {
    int srow = prow + tt - KPAD;
    if (srow >= 0 && srow < N_TOK) {
      float w = wr[tt];
      const float* vrow = &vh[(size_t)srow * DH + dbase];
#pragma unroll
      for (int u = 0; u < 8; ++u) acc[u] += w * vrow[u];
    }
  }
  float* outp = &ao[(size_t)prow * DIMF + h * DH + dbase];
#pragma unroll
  for (int u = 0; u < 8; ++u) outp[u] = acc[u];
}

// ---------------- final projection + un-sort scatter ----------------
__global__ __launch_bounds__(256)
void k_proj(const float* __restrict__ ao, const float* __restrict__ wout,
            const float* __restrict__ bout, const int* __restrict__ idx,
            float* __restrict__ out) {
  __shared__ float As[16][65];
  __shared__ float Bs[16][65];
  __shared__ int rowIdx[64];
  int tid = threadIdx.x;
  int p0 = blockIdx.y * 64, j0 = blockIdx.x * 64;
  if (tid < 64) rowIdx[tid] = idx[p0 + tid];
  __syncthreads();
  int ty = tid >> 4, tx = tid & 15;
  float acc[4][4] = {};
  for (int k0 = 0; k0 < DIMF; k0 += 16) {
#pragma unroll
    for (int l = 0; l < 4; ++l) {
      int lin = tid + l * 256;
      int row = lin >> 4, kk = lin & 15;
      As[kk][row] = ao[(size_t)(p0 + row) * DIMF + k0 + kk];
      Bs[kk][row] = wout[(size_t)(j0 + row) * DIMF + k0 + kk];
    }
    __syncthreads();
#pragma unroll
    for (int kk = 0; kk < 16; ++kk) {
      float a[4], b[4];
#pragma unroll
      for (int i = 0; i < 4; ++i) a[i] = As[kk][ty * 4 + i];
#pragma unroll
      for (int j = 0; j < 4; ++j) b[j] = Bs[kk][tx * 4 + j];
#pragma unroll
      for (int i = 0; i < 4; ++i)
#pragma unroll
        for (int j = 0; j < 4; ++j) acc[i][j] += a[i] * b[j];
    }
    __syncthreads();
  }
  float4 bv = *(const float4*)&bout[j0 + tx * 4];
#pragma unroll
  for (int i = 0; i < 4; ++i) {
    int orow = rowIdx[ty * 4 + i];
    float4 o;
    o.x = acc[i][0] + bv.x; o.y = acc[i][1] + bv.y;
    o.z = acc[i][2] + bv.z; o.w = acc[i][3] + bv.w;
    *(float4*)&out[(size_t)orow * DIMF + j0 + tx * 4] = o;
  }
}

extern "C" void kernel_launch(void* const* d_in, const int* in_sizes, int n_in,
                              void* d_out, int out_size, void* d_ws, size_t ws_size,
                              hipStream_t stream) {
  const float* x     = (const float*)d_in[0];
  const int*   labels= (const int*)d_in[1];
  const float* wqkv  = (const float*)d_in[2];
  const float* wres  = (const float*)d_in[3];
  const float* wout  = (const float*)d_in[4];
  const float* bout  = (const float*)d_in[5];
  float* out = (float*)d_out;

  char* base = (char*)d_ws;
  size_t off = 0;
  auto alloc = [&](size_t bytes) -> void* {
    void* p = base + off;
    off = (off + bytes + 255) & ~(size_t)255;
    return p;
  };
  int* idx      = (int*)alloc((size_t)N_TOK * 4);
  int* counts   = (int*)alloc(NCLUST * 4);
  int* offsets  = (int*)alloc(NCLUST * 4);
  unsigned* maxes = (unsigned*)alloc(256);
  size_t qkvBytes = (size_t)HEADS * N_TOK * DH * 4;   // 32 MB each
  float* q    = (float*)alloc(qkvBytes);
  float* kbuf = (float*)alloc(qkvBytes);   // reused: xz/tm1/tm2 during pinv, then ao
  float* v    = (float*)alloc(qkvBytes);
  size_t lmBytes = (size_t)HEADS * NCLUST * DH * 4;   // 1 MB each
  float* ql = (float*)alloc(lmBytes);
  float* kl = (float*)alloc(lmBytes);
  float* t1 = (float*)alloc(lmBytes);
  float* t2 = (float*)alloc(lmBytes);
  size_t matB = (size_t)HEADS * NCLUST * NCLUST * 4;  // 8 MB
  float* a2 = (float*)alloc(matB);
  float* zA = (float*)alloc(matB);
  float* zB = (float*)alloc(matB);
  // overlays inside kbuf (free after k_t1):
  float* xz  = kbuf;
  float* tm1 = (float*)((char*)kbuf + matB);
  float* tm2 = (float*)((char*)kbuf + 2 * matB);
  float* ao  = kbuf;   // 32 MB, used after pinv

  hipMemsetAsync(counts, 0, NCLUST * 4, stream);
  hipMemsetAsync(maxes, 0, 8, stream);

  k_hist<<<dim3(64), dim3(256), 0, stream>>>(labels, counts);
  k_scan<<<dim3(1), dim3(512), 0, stream>>>(counts, offsets);
  k_build_idx<<<dim3(NCLUST), dim3(64), 0, stream>>>(labels, offsets, idx);
  k_qkv<<<dim3(QKV_COLS / 64, N_TOK / 64), dim3(256), 0, stream>>>(x, wqkv, idx, q, kbuf, v);
  k_landmarks<<<dim3(NCLUST, HEADS), dim3(64), 0, stream>>>(q, kbuf, offsets, counts, ql, kl);
  k_a2<<<dim3(NCLUST, HEADS), dim3(256), 0, stream>>>(ql, kl, a2);
  k_colrow_max<<<dim3(NCLUST / 64, HEADS), dim3(64), 0, stream>>>(a2, maxes);
  k_z0<<<dim3(16, 16, HEADS), dim3(256), 0, stream>>>(a2, maxes, zA);
  // t1 before pinv so kbuf can be reused for pinv temporaries
  k_t1<<<dim3(NCLUST / 16, HEADS), dim3(256), 0, stream>>>(ql, kbuf, v, t1);

  float* zin = zA;
  float* zout = zB;
  dim3 g8(8, 8, HEADS), b256(256);
  for (int it = 0; it < PINV_IT; ++it) {
    k_gemm512<<<g8, b256, 0, stream>>>(a2, zin, xz, 0.f, -1.f);       // xz = a2@z
    k_gemm512<<<g8, b256, 0, stream>>>(xz, xz, tm1, 7.f, 1.f);        // 7xz - xz@xz
    k_gemm512<<<g8, b256, 0, stream>>>(xz, tm1, tm2, 15.f, 1.f);      // 15xz - xz@tm1
    k_gemm512<<<g8, b256, 0, stream>>>(zin, tm2, zout, 13.f, 0.25f);  // 0.25*(13z - z@tm2)
    float* tswap = zin; zin = zout; zout = tswap;
  }
  // zin == zA after 6 iterations (not inside kbuf/ao overlay)

  k_t2<<<dim3(NCLUST, HEADS), dim3(64), 0, stream>>>(zin, t1, t2);
  k_out_attn<<<dim3(N_TOK / 32, HEADS), dim3(256), 0, stream>>>(q, kl, t2, v, wres, ao);
  k_proj<<<dim3(DIMF / 64, N_TOK / 64), dim3(256), 0, stream>>>(ao, wout, bout, idx, out);
}

// Round 7
// 2937.169 us; speedup vs baseline: 1.7372x; 1.7372x over previous
//
#include <hip/hip_runtime.h>
#include <hip/hip_bf16.h>
#include <math.h>

// Nystrom attention, fp32 implementation.
// R1: k_out_attn rewritten flash-style (was 1 block/CU, 92KB LDS, 1.2e8 bank
// conflicts, 1872us). Now 52KB LDS -> 3 blocks/CU, online softmax, 4x4
// register tiles, +16-stride lane mapping for conflict-free LDS reads.
// R2-R6: GPUAcquisitionTimeout x5. R3 added split-bf16 MFMA pinv chain.
// R6: byte-identical resubmit #4 — two unverified rewrites in flight;
// maximizing P(pass)*attribution on the next successful slot.

#define N_TOK   16384
#define DIMF    512
#define HEADS   8
#define DH      64
#define NCLUST  512
#define QKV_COLS 1536
#define PINV_IT 6
#define KW      33
#define KPAD    16

typedef short bh8 __attribute__((ext_vector_type(8)));
typedef float f32x4 __attribute__((ext_vector_type(4)));

// round-to-nearest-even bf16 split: x ~= hi + lo, both bf16
__device__ inline void split2(float x, ushort& hi, ushort& lo) {
  union { float f; unsigned u; } a; a.f = x;
  unsigned rh = a.u + 0x7FFFu + ((a.u >> 16) & 1u);
  hi = (ushort)(rh >> 16);
  union { unsigned u; float f; } hb; hb.u = ((unsigned)hi) << 16;
  float r = x - hb.f;
  union { float f; unsigned u; } b; b.f = r;
  unsigned rl = b.u + 0x7FFFu + ((b.u >> 16) & 1u);
  lo = (ushort)(rl >> 16);
}

// ---------------- sort ----------------
__global__ void k_hist(const int* __restrict__ labels, int* __restrict__ counts) {
  int i = blockIdx.x * blockDim.x + threadIdx.x;
  if (i < N_TOK) atomicAdd(&counts[labels[i]], 1);
}

__global__ void k_scan(const int* __restrict__ counts, int* __restrict__ offsets) {
  __shared__ int s[NCLUST];
  int t = threadIdx.x;
  s[t] = counts[t];
  __syncthreads();
  for (int off = 1; off < NCLUST; off <<= 1) {
    int v = (t >= off) ? s[t - off] : 0;
    __syncthreads();
    s[t] += v;
    __syncthreads();
  }
  offsets[t] = s[t] - counts[t];  // exclusive
}

// one wave per cluster; in-order ballot scan reproduces stable argsort
__global__ void k_build_idx(const int* __restrict__ labels, const int* __restrict__ offsets,
                            int* __restrict__ idx) {
  int c = blockIdx.x;
  int lane = threadIdx.x;  // 64
  int base = offsets[c];
  for (int j0 = 0; j0 < N_TOK; j0 += 64) {
    int lbl = labels[j0 + lane];
    unsigned long long mask = __ballot(lbl == c);
    if (lbl == c) {
      int pos = base + (int)__popcll(mask & ((1ULL << lane) - 1ULL));
      idx[pos] = j0 + lane;
    }
    base += (int)__popcll(mask);
  }
}

// ---------------- QKV GEMM with row gather ----------------
__global__ __launch_bounds__(256)
void k_qkv(const float* __restrict__ x, const float* __restrict__ wqkv,
           const int* __restrict__ idx,
           float* __restrict__ q, float* __restrict__ k, float* __restrict__ v) {
  __shared__ float As[16][65];
  __shared__ float Bs[16][65];
  __shared__ int rowIdx[64];
  int tid = threadIdx.x;
  int p0 = blockIdx.y * 64;
  int j0 = blockIdx.x * 64;
  if (tid < 64) rowIdx[tid] = idx[p0 + tid];
  __syncthreads();
  int ty = tid >> 4, tx = tid & 15;
  float acc[4][4] = {};
  for (int k0 = 0; k0 < DIMF; k0 += 16) {
#pragma unroll
    for (int l = 0; l < 4; ++l) {
      int lin = tid + l * 256;
      int row = lin >> 4, kk = lin & 15;
      As[kk][row] = x[(size_t)rowIdx[row] * DIMF + k0 + kk];
      Bs[kk][row] = wqkv[(size_t)(j0 + row) * DIMF + k0 + kk];
    }
    __syncthreads();
#pragma unroll
    for (int kk = 0; kk < 16; ++kk) {
      float a[4], b[4];
#pragma unroll
      for (int i = 0; i < 4; ++i) a[i] = As[kk][ty * 4 + i];
#pragma unroll
      for (int j = 0; j < 4; ++j) b[j] = Bs[kk][tx * 4 + j];
#pragma unroll
      for (int i = 0; i < 4; ++i)
#pragma unroll
        for (int j = 0; j < 4; ++j) acc[i][j] += a[i] * b[j];
    }
    __syncthreads();
  }
  int which = j0 >> 9;            // 0=q 1=k 2=v  (block spans one 64-col slab)
  int h = (j0 >> 6) & 7;
  float* dst = (which == 0) ? q : (which == 1) ? k : v;
#pragma unroll
  for (int i = 0; i < 4; ++i) {
    int p = p0 + ty * 4 + i;
    float4 val = make_float4(acc[i][0], acc[i][1], acc[i][2], acc[i][3]);
    *(float4*)&dst[(((size_t)h * N_TOK) + p) * DH + tx * 4] = val;
  }
}

// ---------------- landmarks (segment means over sorted ranges) ----------------
__global__ void k_landmarks(const float* __restrict__ q, const float* __restrict__ k,
                            const int* __restrict__ offsets, const int* __restrict__ counts,
                            float* __restrict__ ql, float* __restrict__ kl) {
  int c = blockIdx.x, h = blockIdx.y, d = threadIdx.x;
  int off = offsets[c], cnt = counts[c];
  const float* qp = q + ((size_t)h * N_TOK) * DH + d;
  const float* kp = k + ((size_t)h * N_TOK) * DH + d;
  float sq = 0.f, sk = 0.f;
  for (int i = 0; i < cnt; ++i) {
    sq += qp[(size_t)(off + i) * DH];
    sk += kp[(size_t)(off + i) * DH];
  }
  float inv = 1.f / (float)(cnt > 0 ? cnt : 1);
  ql[(((size_t)h * NCLUST) + c) * DH + d] = sq * inv;
  kl[(((size_t)h * NCLUST) + c) * DH + d] = sk * inv;
}

// ---------------- a2 = softmax(q_l @ k_l^T) rows ----------------
__global__ __launch_bounds__(256)
void k_a2(const float* __restrict__ ql, const float* __restrict__ kl, float* __restrict__ a2) {
  int r = blockIdx.x, h = blockIdx.y, t = threadIdx.x;
  __shared__ float qrow[DH];
  __shared__ float red[256];
  if (t < DH) qrow[t] = ql[(((size_t)h * NCLUST) + r) * DH + t];
  __syncthreads();
  const float* klh = kl + (size_t)h * NCLUST * DH;
  float s0 = 0, s1 = 0;
  for (int d = 0; d < DH; ++d) {
    float qd = qrow[d];
    s0 += qd * klh[(size_t)t * DH + d];
    s1 += qd * klh[(size_t)(t + 256) * DH + d];
  }
  red[t] = fmaxf(s0, s1);
  __syncthreads();
  for (int o = 128; o > 0; o >>= 1) { if (t < o) red[t] = fmaxf(red[t], red[t + o]); __syncthreads(); }
  float m = red[0];
  __syncthreads();
  float e0 = __expf(s0 - m), e1 = __expf(s1 - m);
  red[t] = e0 + e1;
  __syncthreads();
  for (int o = 128; o > 0; o >>= 1) { if (t < o) red[t] += red[t + o]; __syncthreads(); }
  float inv = 1.f / red[0];
  float* row = a2 + (((size_t)h * NCLUST) + r) * NCLUST;
  row[t] = e0 * inv;
  row[t + 256] = e1 * inv;
}

// ---------------- pinv init: global max col/row sums ----------------
__global__ void k_colrow_max(const float* __restrict__ a2, unsigned* __restrict__ maxes) {
  int h = blockIdx.y;
  int c = blockIdx.x * 64 + threadIdx.x;
  const float* A = a2 + (size_t)h * NCLUST * NCLUST;
  float s = 0;
  for (int r = 0; r < NCLUST; ++r) s += A[(size_t)r * NCLUST + c];
  atomicMax(&maxes[0], __float_as_uint(s));
  float rs = 0;
  for (int j = 0; j < NCLUST; ++j) rs += A[(size_t)c * NCLUST + j];
  atomicMax(&maxes[1], __float_as_uint(rs));
}

__global__ __launch_bounds__(256)
void k_z0(const float* __restrict__ a2, const unsigned* __restrict__ maxes, float* __restrict__ z) {
  __shared__ float s[32][33];
  int h = blockIdx.z;
  int i0 = blockIdx.x * 32, j0 = blockIdx.y * 32;
  float inv = 1.f / (__uint_as_float(maxes[0]) * __uint_as_float(maxes[1]));
  const float* A = a2 + (size_t)h * NCLUST * NCLUST;
  float* Z = z + (size_t)h * NCLUST * NCLUST;
  int t = threadIdx.x;
#pragma unroll
  for (int l = 0; l < 4; ++l) {
    int lin = t + l * 256;
    int a = lin >> 5, b = lin & 31;
    s[a][b] = A[(size_t)(j0 + a) * NCLUST + i0 + b];
  }
  __syncthreads();
#pragma unroll
  for (int l = 0; l < 4; ++l) {
    int lin = t + l * 256;
    int a = lin >> 5, b = lin & 31;
    Z[(size_t)(i0 + a) * NCLUST + j0 + b] = s[b][a] * inv;
  }
}

// ------- batched 512x512 GEMM via split-bf16 MFMA: C = scale*(alpha*A - A@B) -------
// A ~= Ah+Al, B ~= Bh+Bl (bf16 each); A@B ~= Ah@Bh + Ah@Bl + Al@Bh (fp32 acc).
// 64x64 tile/block, 4 waves x (32x32), mfma_f32_16x16x32_bf16.
// LDS rows padded to 40 ushorts (80B: 16B-aligned b128 reads, bank stride 20).
__global__ __launch_bounds__(256)
void k_gemm512_mfma(const float* __restrict__ A, const float* __restrict__ B,
                    float* __restrict__ C, float alpha, float scale) {
  __shared__ __align__(16) ushort As_hi[64][40];
  __shared__ __align__(16) ushort As_lo[64][40];
  __shared__ __align__(16) ushort Bs_hi[64][40];
  __shared__ __align__(16) ushort Bs_lo[64][40];
  int h = blockIdx.z;
  const float* Ahp = A + (size_t)h * NCLUST * NCLUST;
  const float* Bhp = B + (size_t)h * NCLUST * NCLUST;
  float* Chp = C + (size_t)h * NCLUST * NCLUST;
  int tid = threadIdx.x;
  int m0 = blockIdx.y * 64, n0 = blockIdx.x * 64;
  int wave = tid >> 6, lane = tid & 63;
  int m_off = (wave >> 1) * 32, n_off = (wave & 1) * 32;
  int lr = lane & 15;          // row (A) / col (B) within fragment
  int ksb = (lane >> 4) * 8;   // k sub-slice base
  // staging indices
  int r0a = tid >> 3, kqa = tid & 7;   // A: rows r0a, r0a+32; float4 kqa
  int k0b = tid >> 4, nqb = tid & 15;  // B: k-rows k0b, k0b+16; float4 nqb
  f32x4 acc[2][2];
#pragma unroll
  for (int i = 0; i < 2; ++i)
#pragma unroll
    for (int j = 0; j < 2; ++j) acc[i][j] = (f32x4)0.f;

  for (int kk0 = 0; kk0 < NCLUST; kk0 += 32) {
    __syncthreads();
#pragma unroll
    for (int half = 0; half < 2; ++half) {
      int row = r0a + half * 32;
      float4 a4 = *(const float4*)&Ahp[(size_t)(m0 + row) * NCLUST + kk0 + kqa * 4];
      ushort4 hv, lv;
      split2(a4.x, hv.x, lv.x); split2(a4.y, hv.y, lv.y);
      split2(a4.z, hv.z, lv.z); split2(a4.w, hv.w, lv.w);
      *(ushort4*)&As_hi[row][kqa * 4] = hv;
      *(ushort4*)&As_lo[row][kqa * 4] = lv;
    }
#pragma unroll
    for (int half = 0; half < 2; ++half) {
      int krow = k0b + half * 16;
      float4 b4 = *(const float4*)&Bhp[(size_t)(kk0 + krow) * NCLUST + n0 + nqb * 4];
      ushort hx, lx;
      split2(b4.x, hx, lx); Bs_hi[nqb * 4 + 0][krow] = hx; Bs_lo[nqb * 4 + 0][krow] = lx;
      split2(b4.y, hx, lx); Bs_hi[nqb * 4 + 1][krow] = hx; Bs_lo[nqb * 4 + 1][krow] = lx;
      split2(b4.z, hx, lx); Bs_hi[nqb * 4 + 2][krow] = hx; Bs_lo[nqb * 4 + 2][krow] = lx;
      split2(b4.w, hx, lx); Bs_hi[nqb * 4 + 3][krow] = hx; Bs_lo[nqb * 4 + 3][krow] = lx;
    }
    __syncthreads();
    bh8 ahi[2], alo[2], bhi[2], blo[2];
#pragma unroll
    for (int i = 0; i < 2; ++i) {
      ahi[i] = *(const bh8*)&As_hi[m_off + i * 16 + lr][ksb];
      alo[i] = *(const bh8*)&As_lo[m_off + i * 16 + lr][ksb];
    }
#pragma unroll
    for (int j = 0; j < 2; ++j) {
      bhi[j] = *(const bh8*)&Bs_hi[n_off + j * 16 + lr][ksb];
      blo[j] = *(const bh8*)&Bs_lo[n_off + j * 16 + lr][ksb];
    }
#pragma unroll
    for (int i = 0; i < 2; ++i)
#pragma unroll
      for (int j = 0; j < 2; ++j) {
        acc[i][j] = __builtin_amdgcn_mfma_f32_16x16x32_bf16(ahi[i], bhi[j], acc[i][j], 0, 0, 0);
        acc[i][j] = __builtin_amdgcn_mfma_f32_16x16x32_bf16(ahi[i], blo[j], acc[i][j], 0, 0, 0);
        acc[i][j] = __builtin_amdgcn_mfma_f32_16x16x32_bf16(alo[i], bhi[j], acc[i][j], 0, 0, 0);
      }
  }
  // epilogue: C = scale*(alpha*A - acc); D frag: row=(lane>>4)*4+r, col=lane&15
#pragma unroll
  for (int i = 0; i < 2; ++i)
#pragma unroll
    for (int j = 0; j < 2; ++j)
#pragma unroll
      for (int r = 0; r < 4; ++r) {
        int m = m0 + m_off + i * 16 + (lane >> 4) * 4 + r;
        int n = n0 + n_off + j * 16 + lr;
        float base = (alpha != 0.f) ? alpha * Ahp[(size_t)m * NCLUST + n] : 0.f;
        Chp[(size_t)m * NCLUST + n] = scale * (base - acc[i][j][r]);
      }
}

// ---------------- t1 = softmax(q_l@k^T) @ v  (flash, 16 q-rows/block) ----------------
__global__ __launch_bounds__(256)
void k_t1(const float* __restrict__ ql, const float* __restrict__ k, const float* __restrict__ v,
          float* __restrict__ t1) {
  __shared__ float qs[16][68];
  __shared__ float ks[64][68];
  __shared__ float vs[64][68];
  __shared__ float P[16][68];
  __shared__ float red[16][17];
  __shared__ float mrun[16], srun[16], fs[16];
  int h = blockIdx.y;
  int r0 = blockIdx.x * 16;
  int t = threadIdx.x;
#pragma unroll
  for (int l = 0; l < 4; ++l) {
    int lin = t + l * 256;  // 1024 = 16*64
    int r = lin >> 6, d = lin & 63;
    qs[r][d] = ql[(((size_t)h * NCLUST) + r0 + r) * DH + d];
  }
  if (t < 16) { mrun[t] = -1e30f; srun[t] = 0.f; }
  float acc0 = 0, acc1 = 0, acc2 = 0, acc3 = 0;
  int rr = t & 15;
  int jg = t >> 4;  // 0..15
  const float* kh = k + (size_t)h * N_TOK * DH;
  const float* vh = v + (size_t)h * N_TOK * DH;
  __syncthreads();
  for (int j0 = 0; j0 < N_TOK; j0 += 64) {
#pragma unroll
    for (int l = 0; l < 16; ++l) {
      int lin = t + l * 256;  // 4096 = 64*64
      int j = lin >> 6, d = lin & 63;
      ks[j][d] = kh[(size_t)(j0 + j) * DH + d];
      vs[j][d] = vh[(size_t)(j0 + j) * DH + d];
    }
    __syncthreads();
    // dots
    float sv[4];
#pragma unroll
    for (int jj = 0; jj < 4; ++jj) {
      int j = jg * 4 + jj;
      const float4* qv = (const float4*)&qs[rr][0];
      const float4* kv = (const float4*)&ks[j][0];
      float s = 0;
#pragma unroll
      for (int d4 = 0; d4 < 16; ++d4) {
        float4 a = qv[d4], b = kv[d4];
        s += a.x * b.x + a.y * b.y + a.z * b.z + a.w * b.w;
      }
      sv[jj] = s;
    }
    red[rr][jg] = fmaxf(fmaxf(sv[0], sv[1]), fmaxf(sv[2], sv[3]));
    __syncthreads();
    if (t < 16) {
      float cm = red[t][0];
      for (int g = 1; g < 16; ++g) cm = fmaxf(cm, red[t][g]);
      float mo = mrun[t];
      float mn = fmaxf(mo, cm);
      float f = __expf(mo - mn);
      mrun[t] = mn; fs[t] = f; srun[t] *= f;
    }
    __syncthreads();
    float mn = mrun[rr];
    float ls = 0;
#pragma unroll
    for (int jj = 0; jj < 4; ++jj) {
      float e = __expf(sv[jj] - mn);
      P[rr][jg * 4 + jj] = e;
      ls += e;
    }
    red[rr][jg] = ls;
    __syncthreads();
    if (t < 16) {
      float cs = 0;
      for (int g = 0; g < 16; ++g) cs += red[t][g];
      srun[t] += cs;
    }
    // PV with rescale; (rr, dg=jg) owns 4 d's
    float f = fs[rr];
    int dbase = jg * 4;
    float a0 = acc0 * f, a1 = acc1 * f, a2v = acc2 * f, a3v = acc3 * f;
#pragma unroll 8
    for (int j = 0; j < 64; ++j) {
      float p = P[rr][j];
      const float* vrow = &vs[j][dbase];
      a0 += p * vrow[0]; a1 += p * vrow[1]; a2v += p * vrow[2]; a3v += p * vrow[3];
    }
    acc0 = a0; acc1 = a1; acc2 = a2v; acc3 = a3v;
    __syncthreads();
  }
  float inv = 1.f / srun[rr];
  float* outp = &t1[(((size_t)h * NCLUST) + r0 + rr) * DH + jg * 4];
  outp[0] = acc0 * inv; outp[1] = acc1 * inv; outp[2] = acc2 * inv; outp[3] = acc3 * inv;
}

// ---------------- t2 = z @ t1 ----------------
__global__ void k_t2(const float* __restrict__ z, const float* __restrict__ t1, float* __restrict__ t2) {
  int r = blockIdx.x, h = blockIdx.y, d = threadIdx.x;
  const float* zr = z + (((size_t)h * NCLUST) + r) * NCLUST;
  const float* t1h = t1 + (size_t)h * NCLUST * DH;
  float s = 0;
  for (int c = 0; c < NCLUST; ++c) s += zr[c] * t1h[(size_t)c * DH + d];
  t2[(((size_t)h * NCLUST) + r) * DH + d] = s;
}

// ---------------- out = softmax(q@k_l^T)@t2 + conv33(v) ----------------
// Flash-style: 64 q-rows/block, online softmax over 8 chunks of 64 landmarks.
// Thread (ty,tx) owns rows {ty+16i} and cols {tx+16j} (stride-16 mapping keeps
// LDS accesses <=2-way per bank = free). LDS 3x(64x68) fp32 = 52KB -> 3 blk/CU.
__global__ __launch_bounds__(256)
void k_out_attn(const float* __restrict__ q, const float* __restrict__ kl,
                const float* __restrict__ t2, const float* __restrict__ v,
                const float* __restrict__ wres, float* __restrict__ ao) {
  __shared__ float qs[64][68];
  __shared__ float ks[64][68];   // reused as t2-chunk buffer
  __shared__ float Ps[64][68];
  __shared__ float wr[KW];
  int h = blockIdx.y;
  int p0 = blockIdx.x * 64;
  int t = threadIdx.x;
  int ty = t >> 4, tx = t & 15;
  const float* qh  = q  + (size_t)h * N_TOK * DH;
  const float* klh = kl + (size_t)h * NCLUST * DH;
  const float* t2h = t2 + (size_t)h * NCLUST * DH;
  const float* vh  = v  + (size_t)h * N_TOK * DH;
  if (t < KW) wr[t] = wres[h * KW + t];
  // stage q tile (64 rows x 64 d)
#pragma unroll
  for (int l = 0; l < 4; ++l) {
    int f4 = t + l * 256;
    int r = f4 >> 4, d4 = f4 & 15;
    *(float4*)&qs[r][d4 * 4] = *(const float4*)&qh[(size_t)(p0 + r) * DH + d4 * 4];
  }
  float m_run[4], s_run[4], accp[4][4];
#pragma unroll
  for (int i = 0; i < 4; ++i) {
    m_run[i] = -1e30f; s_run[i] = 0.f;
#pragma unroll
    for (int j = 0; j < 4; ++j) accp[i][j] = 0.f;
  }
  __syncthreads();

  for (int c0 = 0; c0 < NCLUST; c0 += 64) {
    // load kl chunk
#pragma unroll
    for (int l = 0; l < 4; ++l) {
      int f4 = t + l * 256;
      int r = f4 >> 4, d4 = f4 & 15;
      *(float4*)&ks[r][d4 * 4] = *(const float4*)&klh[(size_t)(c0 + r) * DH + d4 * 4];
    }
    __syncthreads();
    // S chunk: 4x4 dots over d
    float sc[4][4] = {};
#pragma unroll
    for (int d4 = 0; d4 < 16; ++d4) {
      float4 a[4], b[4];
#pragma unroll
      for (int i = 0; i < 4; ++i) a[i] = *(const float4*)&qs[ty + 16 * i][d4 * 4];
#pragma unroll
      for (int j = 0; j < 4; ++j) b[j] = *(const float4*)&ks[tx + 16 * j][d4 * 4];
#pragma unroll
      for (int i = 0; i < 4; ++i)
#pragma unroll
        for (int j = 0; j < 4; ++j)
          sc[i][j] += a[i].x * b[j].x + a[i].y * b[j].y + a[i].z * b[j].z + a[i].w * b[j].w;
    }
    // online softmax per row (reduce across the 16-lane tx group)
#pragma unroll
    for (int i = 0; i < 4; ++i) {
      float cm = fmaxf(fmaxf(sc[i][0], sc[i][1]), fmaxf(sc[i][2], sc[i][3]));
      cm = fmaxf(cm, __shfl_xor(cm, 1, 16));
      cm = fmaxf(cm, __shfl_xor(cm, 2, 16));
      cm = fmaxf(cm, __shfl_xor(cm, 4, 16));
      cm = fmaxf(cm, __shfl_xor(cm, 8, 16));
      float mo = m_run[i];
      float mn = fmaxf(mo, cm);
      float f = __expf(mo - mn);
      m_run[i] = mn;
      float ls = 0.f;
#pragma unroll
      for (int j = 0; j < 4; ++j) {
        float e = __expf(sc[i][j] - mn);
        Ps[ty + 16 * i][tx + 16 * j] = e;
        ls += e;
      }
      ls += __shfl_xor(ls, 1, 16);
      ls += __shfl_xor(ls, 2, 16);
      ls += __shfl_xor(ls, 4, 16);
      ls += __shfl_xor(ls, 8, 16);
      s_run[i] = s_run[i] * f + ls;
#pragma unroll
      for (int j = 0; j < 4; ++j) accp[i][j] *= f;
    }
    __syncthreads();
    // load t2 chunk into ks buffer
#pragma unroll
    for (int l = 0; l < 4; ++l) {
      int f4 = t + l * 256;
      int r = f4 >> 4, d4 = f4 & 15;
      *(float4*)&ks[r][d4 * 4] = *(const float4*)&t2h[(size_t)(c0 + r) * DH + d4 * 4];
    }
    __syncthreads();
    // PV: accp[i][j] += sum_c P[row_i][c] * t2[c][d_j]
#pragma unroll 8
    for (int kk = 0; kk < 64; ++kk) {
      float a[4], b[4];
#pragma unroll
      for (int i = 0; i < 4; ++i) a[i] = Ps[ty + 16 * i][kk];
#pragma unroll
      for (int j = 0; j < 4; ++j) b[j] = ks[kk][tx + 16 * j];
#pragma unroll
      for (int i = 0; i < 4; ++i)
#pragma unroll
        for (int j = 0; j < 4; ++j) accp[i][j] += a[i] * b[j];
    }
    __syncthreads();
  }
  // finalize: 1/sum, conv residual, store
#pragma unroll
  for (int i = 0; i < 4; ++i) {
    float inv = 1.f / s_run[i];
#pragma unroll
    for (int j = 0; j < 4; ++j) accp[i][j] *= inv;
  }
#pragma unroll
  for (int i = 0; i < 4; ++i) {
    int prow = p0 + ty + 16 * i;
    for (int tap = 0; tap < KW; ++tap) {
      int srow = prow + tap - KPAD;
      if (srow >= 0 && srow < N_TOK) {
        float w = wr[tap];
        const float* vrow = &vh[(size_t)srow * DH];
#pragma unroll
        for (int j = 0; j < 4; ++j) accp[i][j] += w * vrow[tx + 16 * j];
      }
    }
  }
#pragma unroll
  for (int i = 0; i < 4; ++i) {
    int prow = p0 + ty + 16 * i;
    float* outp = &ao[(size_t)prow * DIMF + h * DH];
#pragma unroll
    for (int j = 0; j < 4; ++j) outp[tx + 16 * j] = accp[i][j];
  }
}

// ---------------- final projection + un-sort scatter ----------------
__global__ __launch_bounds__(256)
void k_proj(const float* __restrict__ ao, const float* __restrict__ wout,
            const float* __restrict__ bout, const int* __restrict__ idx,
            float* __restrict__ out) {
  __shared__ float As[16][65];
  __shared__ float Bs[16][65];
  __shared__ int rowIdx[64];
  int tid = threadIdx.x;
  int p0 = blockIdx.y * 64, j0 = blockIdx.x * 64;
  if (tid < 64) rowIdx[tid] = idx[p0 + tid];
  __syncthreads();
  int ty = tid >> 4, tx = tid & 15;
  float acc[4][4] = {};
  for (int k0 = 0; k0 < DIMF; k0 += 16) {
#pragma unroll
    for (int l = 0; l < 4; ++l) {
      int lin = tid + l * 256;
      int row = lin >> 4, kk = lin & 15;
      As[kk][row] = ao[(size_t)(p0 + row) * DIMF + k0 + kk];
      Bs[kk][row] = wout[(size_t)(j0 + row) * DIMF + k0 + kk];
    }
    __syncthreads();
#pragma unroll
    for (int kk = 0; kk < 16; ++kk) {
      float a[4], b[4];
#pragma unroll
      for (int i = 0; i < 4; ++i) a[i] = As[kk][ty * 4 + i];
#pragma unroll
      for (int j = 0; j < 4; ++j) b[j] = Bs[kk][tx * 4 + j];
#pragma unroll
      for (int i = 0; i < 4; ++i)
#pragma unroll
        for (int j = 0; j < 4; ++j) acc[i][j] += a[i] * b[j];
    }
    __syncthreads();
  }
  float4 bv = *(const float4*)&bout[j0 + tx * 4];
#pragma unroll
  for (int i = 0; i < 4; ++i) {
    int orow = rowIdx[ty * 4 + i];
    float4 o;
    o.x = acc[i][0] + bv.x; o.y = acc[i][1] + bv.y;
    o.z = acc[i][2] + bv.z; o.w = acc[i][3] + bv.w;
    *(float4*)&out[(size_t)orow * DIMF + j0 + tx * 4] = o;
  }
}

extern "C" void kernel_launch(void* const* d_in, const int* in_sizes, int n_in,
                              void* d_out, int out_size, void* d_ws, size_t ws_size,
                              hipStream_t stream) {
  const float* x     = (const float*)d_in[0];
  const int*   labels= (const int*)d_in[1];
  const float* wqkv  = (const float*)d_in[2];
  const float* wres  = (const float*)d_in[3];
  const float* wout  = (const float*)d_in[4];
  const float* bout  = (const float*)d_in[5];
  float* out = (float*)d_out;

  char* base = (char*)d_ws;
  size_t off = 0;
  auto alloc = [&](size_t bytes) -> void* {
    void* p = base + off;
    off = (off + bytes + 255) & ~(size_t)255;
    return p;
  };
  int* idx      = (int*)alloc((size_t)N_TOK * 4);
  int* counts   = (int*)alloc(NCLUST * 4);
  int* offsets  = (int*)alloc(NCLUST * 4);
  unsigned* maxes = (unsigned*)alloc(256);
  size_t qkvBytes = (size_t)HEADS * N_TOK * DH * 4;   // 32 MB each
  float* q    = (float*)alloc(qkvBytes);
  float* kbuf = (float*)alloc(qkvBytes);   // reused: xz/tm1/tm2 during pinv, then ao
  float* v    = (float*)alloc(qkvBytes);
  size_t lmBytes = (size_t)HEADS * NCLUST * DH * 4;   // 1 MB each
  float* ql = (float*)alloc(lmBytes);
  float* kl = (float*)alloc(lmBytes);
  float* t1 = (float*)alloc(lmBytes);
  float* t2 = (float*)alloc(lmBytes);
  size_t matB = (size_t)HEADS * NCLUST * NCLUST * 4;  // 8 MB
  float* a2 = (float*)alloc(matB);
  float* zA = (float*)alloc(matB);
  float* zB = (float*)alloc(matB);
  // overlays inside kbuf (free after k_t1):
  float* xz  = kbuf;
  float* tm1 = (float*)((char*)kbuf + matB);
  float* tm2 = (float*)((char*)kbuf + 2 * matB);
  float* ao  = kbuf;   // 32 MB, used after pinv

  hipMemsetAsync(counts, 0, NCLUST * 4, stream);
  hipMemsetAsync(maxes, 0, 8, stream);

  k_hist<<<dim3(64), dim3(256), 0, stream>>>(labels, counts);
  k_scan<<<dim3(1), dim3(512), 0, stream>>>(counts, offsets);
  k_build_idx<<<dim3(NCLUST), dim3(64), 0, stream>>>(labels, offsets, idx);
  k_qkv<<<dim3(QKV_COLS / 64, N_TOK / 64), dim3(256), 0, stream>>>(x, wqkv, idx, q, kbuf, v);
  k_landmarks<<<dim3(NCLUST, HEADS), dim3(64), 0, stream>>>(q, kbuf, offsets, counts, ql, kl);
  k_a2<<<dim3(NCLUST, HEADS), dim3(256), 0, stream>>>(ql, kl, a2);
  k_colrow_max<<<dim3(NCLUST / 64, HEADS), dim3(64), 0, stream>>>(a2, maxes);
  k_z0<<<dim3(16, 16, HEADS), dim3(256), 0, stream>>>(a2, maxes, zA);
  // t1 before pinv so kbuf can be reused for pinv temporaries
  k_t1<<<dim3(NCLUST / 16, HEADS), dim3(256), 0, stream>>>(ql, kbuf, v, t1);

  float* zin = zA;
  float* zout = zB;
  dim3 g8(8, 8, HEADS), b256(256);
  for (int it = 0; it < PINV_IT; ++it) {
    k_gemm512_mfma<<<g8, b256, 0, stream>>>(a2, zin, xz, 0.f, -1.f);       // xz = a2@z
    k_gemm512_mfma<<<g8, b256, 0, stream>>>(xz, xz, tm1, 7.f, 1.f);        // 7xz - xz@xz
    k_gemm512_mfma<<<g8, b256, 0, stream>>>(xz, tm1, tm2, 15.f, 1.f);      // 15xz - xz@tm1
    k_gemm512_mfma<<<g8, b256, 0, stream>>>(zin, tm2, zout, 13.f, 0.25f);  // 0.25*(13z - z@tm2)
    float* tswap = zin; zin = zout; zout = tswap;
  }
  // zin == zA after 6 iterations (not inside kbuf/ao overlay)

  k_t2<<<dim3(NCLUST, HEADS), dim3(64), 0, stream>>>(zin, t1, t2);
  k_out_attn<<<dim3(N_TOK / 64, HEADS), dim3(256), 0, stream>>>(q, kl, t2, v, wres, ao);
  k_proj<<<dim3(DIMF / 64, N_TOK / 64), dim3(256), 0, stream>>>(ao, wout, bout, idx, out);
}

// Round 10
// 2151.080 us; speedup vs baseline: 2.3720x; 1.3654x over previous
//
#include <hip/hip_runtime.h>
#include <hip/hip_bf16.h>
#include <math.h>

// Nystrom attention.
// R1: k_out_attn flash-style rewrite (VERIFIED R7). R3: pinv -> split-bf16 MFMA
// (VERIFIED R7). R7: 5102 -> 2937us; k_t1 top @988us (1 blk/CU, latency-bound).
// R8: (a) k_t1 -> split-K x8 (grid 256->2048) with online-softmax partials
// (pacc in idle zB, pml in idle t2) + combine; (b) k_qkv -> split-bf16 MFMA.
// R8: container failed (infra). R9: GPUAcquisitionTimeout. R10: byte-identical
// resubmit #2 of the R8 kernel (audited; two changes in flight, not stacking).

#define N_TOK   16384
#define DIMF    512
#define HEADS   8
#define DH      64
#define NCLUST  512
#define QKV_COLS 1536
#define PINV_IT 6
#define KW      33
#define KPAD    16
#define SEG     8
#define SEGLEN  (N_TOK / SEG)

typedef short bh8 __attribute__((ext_vector_type(8)));
typedef float f32x4 __attribute__((ext_vector_type(4)));

// round-to-nearest-even bf16 split: x ~= hi + lo, both bf16
__device__ inline void split2(float x, ushort& hi, ushort& lo) {
  union { float f; unsigned u; } a; a.f = x;
  unsigned rh = a.u + 0x7FFFu + ((a.u >> 16) & 1u);
  hi = (ushort)(rh >> 16);
  union { unsigned u; float f; } hb; hb.u = ((unsigned)hi) << 16;
  float r = x - hb.f;
  union { float f; unsigned u; } b; b.f = r;
  unsigned rl = b.u + 0x7FFFu + ((b.u >> 16) & 1u);
  lo = (ushort)(rl >> 16);
}

// ---------------- sort ----------------
__global__ void k_hist(const int* __restrict__ labels, int* __restrict__ counts) {
  int i = blockIdx.x * blockDim.x + threadIdx.x;
  if (i < N_TOK) atomicAdd(&counts[labels[i]], 1);
}

__global__ void k_scan(const int* __restrict__ counts, int* __restrict__ offsets) {
  __shared__ int s[NCLUST];
  int t = threadIdx.x;
  s[t] = counts[t];
  __syncthreads();
  for (int off = 1; off < NCLUST; off <<= 1) {
    int v = (t >= off) ? s[t - off] : 0;
    __syncthreads();
    s[t] += v;
    __syncthreads();
  }
  offsets[t] = s[t] - counts[t];  // exclusive
}

// one wave per cluster; in-order ballot scan reproduces stable argsort
__global__ void k_build_idx(const int* __restrict__ labels, const int* __restrict__ offsets,
                            int* __restrict__ idx) {
  int c = blockIdx.x;
  int lane = threadIdx.x;  // 64
  int base = offsets[c];
  for (int j0 = 0; j0 < N_TOK; j0 += 64) {
    int lbl = labels[j0 + lane];
    unsigned long long mask = __ballot(lbl == c);
    if (lbl == c) {
      int pos = base + (int)__popcll(mask & ((1ULL << lane) - 1ULL));
      idx[pos] = j0 + lane;
    }
    base += (int)__popcll(mask);
  }
}

// -------- QKV GEMM (gathered rows) via split-bf16 MFMA --------
__global__ __launch_bounds__(256)
void k_qkv_mfma(const float* __restrict__ x, const float* __restrict__ wqkv,
                const int* __restrict__ idx,
                float* __restrict__ q, float* __restrict__ k, float* __restrict__ v) {
  __shared__ __align__(16) ushort As_hi[64][40];
  __shared__ __align__(16) ushort As_lo[64][40];
  __shared__ __align__(16) ushort Bs_hi[64][40];
  __shared__ __align__(16) ushort Bs_lo[64][40];
  __shared__ int rowIdx[64];
  int tid = threadIdx.x;
  int p0 = blockIdx.y * 64;   // sorted-domain row block
  int j0 = blockIdx.x * 64;   // qkv col block (one 64-col head slab)
  if (tid < 64) rowIdx[tid] = idx[p0 + tid];
  int wave = tid >> 6, lane = tid & 63;
  int m_off = (wave >> 1) * 32, n_off = (wave & 1) * 32;
  int lr = lane & 15;
  int ksb = (lane >> 4) * 8;
  int r0 = tid >> 3, kq = tid & 7;   // staging: row r0/r0+32, float4 col kq
  f32x4 acc[2][2];
#pragma unroll
  for (int i = 0; i < 2; ++i)
#pragma unroll
    for (int j = 0; j < 2; ++j) acc[i][j] = (f32x4)0.f;

  for (int kk0 = 0; kk0 < DIMF; kk0 += 32) {
    __syncthreads();   // prior reads done (and rowIdx visible on iter 0)
#pragma unroll
    for (int half = 0; half < 2; ++half) {
      int row = r0 + half * 32;
      float4 a4 = *(const float4*)&x[(size_t)rowIdx[row] * DIMF + kk0 + kq * 4];
      ushort4 hv, lv;
      split2(a4.x, hv.x, lv.x); split2(a4.y, hv.y, lv.y);
      split2(a4.z, hv.z, lv.z); split2(a4.w, hv.w, lv.w);
      *(ushort4*)&As_hi[row][kq * 4] = hv;
      *(ushort4*)&As_lo[row][kq * 4] = lv;
      float4 b4 = *(const float4*)&wqkv[(size_t)(j0 + row) * DIMF + kk0 + kq * 4];
      split2(b4.x, hv.x, lv.x); split2(b4.y, hv.y, lv.y);
      split2(b4.z, hv.z, lv.z); split2(b4.w, hv.w, lv.w);
      *(ushort4*)&Bs_hi[row][kq * 4] = hv;
      *(ushort4*)&Bs_lo[row][kq * 4] = lv;
    }
    __syncthreads();
    bh8 ahi[2], alo[2], bhi[2], blo[2];
#pragma unroll
    for (int i = 0; i < 2; ++i) {
      ahi[i] = *(const bh8*)&As_hi[m_off + i * 16 + lr][ksb];
      alo[i] = *(const bh8*)&As_lo[m_off + i * 16 + lr][ksb];
    }
#pragma unroll
    for (int j = 0; j < 2; ++j) {
      bhi[j] = *(const bh8*)&Bs_hi[n_off + j * 16 + lr][ksb];
      blo[j] = *(const bh8*)&Bs_lo[n_off + j * 16 + lr][ksb];
    }
#pragma unroll
    for (int i = 0; i < 2; ++i)
#pragma unroll
      for (int j = 0; j < 2; ++j) {
        acc[i][j] = __builtin_amdgcn_mfma_f32_16x16x32_bf16(ahi[i], bhi[j], acc[i][j], 0, 0, 0);
        acc[i][j] = __builtin_amdgcn_mfma_f32_16x16x32_bf16(ahi[i], blo[j], acc[i][j], 0, 0, 0);
        acc[i][j] = __builtin_amdgcn_mfma_f32_16x16x32_bf16(alo[i], bhi[j], acc[i][j], 0, 0, 0);
      }
  }
  int which = j0 >> 9;            // 0=q 1=k 2=v
  int h = (j0 >> 6) & 7;
  float* dst = (which == 0) ? q : (which == 1) ? k : v;
#pragma unroll
  for (int i = 0; i < 2; ++i)
#pragma unroll
    for (int j = 0; j < 2; ++j)
#pragma unroll
      for (int r = 0; r < 4; ++r) {
        int p = p0 + m_off + i * 16 + (lane >> 4) * 4 + r;
        int c = n_off + j * 16 + lr;
        dst[((size_t)h * N_TOK + p) * DH + c] = acc[i][j][r];
      }
}

// ---------------- landmarks (segment means over sorted ranges) ----------------
__global__ void k_landmarks(const float* __restrict__ q, const float* __restrict__ k,
                            const int* __restrict__ offsets, const int* __restrict__ counts,
                            float* __restrict__ ql, float* __restrict__ kl) {
  int c = blockIdx.x, h = blockIdx.y, d = threadIdx.x;
  int off = offsets[c], cnt = counts[c];
  const float* qp = q + ((size_t)h * N_TOK) * DH + d;
  const float* kp = k + ((size_t)h * N_TOK) * DH + d;
  float sq = 0.f, sk = 0.f;
  for (int i = 0; i < cnt; ++i) {
    sq += qp[(size_t)(off + i) * DH];
    sk += kp[(size_t)(off + i) * DH];
  }
  float inv = 1.f / (float)(cnt > 0 ? cnt : 1);
  ql[(((size_t)h * NCLUST) + c) * DH + d] = sq * inv;
  kl[(((size_t)h * NCLUST) + c) * DH + d] = sk * inv;
}

// ---------------- a2 = softmax(q_l @ k_l^T) rows ----------------
__global__ __launch_bounds__(256)
void k_a2(const float* __restrict__ ql, const float* __restrict__ kl, float* __restrict__ a2) {
  int r = blockIdx.x, h = blockIdx.y, t = threadIdx.x;
  __shared__ float qrow[DH];
  __shared__ float red[256];
  if (t < DH) qrow[t] = ql[(((size_t)h * NCLUST) + r) * DH + t];
  __syncthreads();
  const float* klh = kl + (size_t)h * NCLUST * DH;
  float s0 = 0, s1 = 0;
  for (int d = 0; d < DH; ++d) {
    float qd = qrow[d];
    s0 += qd * klh[(size_t)t * DH + d];
    s1 += qd * klh[(size_t)(t + 256) * DH + d];
  }
  red[t] = fmaxf(s0, s1);
  __syncthreads();
  for (int o = 128; o > 0; o >>= 1) { if (t < o) red[t] = fmaxf(red[t], red[t + o]); __syncthreads(); }
  float m = red[0];
  __syncthreads();
  float e0 = __expf(s0 - m), e1 = __expf(s1 - m);
  red[t] = e0 + e1;
  __syncthreads();
  for (int o = 128; o > 0; o >>= 1) { if (t < o) red[t] += red[t + o]; __syncthreads(); }
  float inv = 1.f / red[0];
  float* row = a2 + (((size_t)h * NCLUST) + r) * NCLUST;
  row[t] = e0 * inv;
  row[t + 256] = e1 * inv;
}

// ---------------- pinv init: global max col/row sums ----------------
__global__ void k_colrow_max(const float* __restrict__ a2, unsigned* __restrict__ maxes) {
  int h = blockIdx.y;
  int c = blockIdx.x * 64 + threadIdx.x;
  const float* A = a2 + (size_t)h * NCLUST * NCLUST;
  float s = 0;
  for (int r = 0; r < NCLUST; ++r) s += A[(size_t)r * NCLUST + c];
  atomicMax(&maxes[0], __float_as_uint(s));
  float rs = 0;
  for (int j = 0; j < NCLUST; ++j) rs += A[(size_t)c * NCLUST + j];
  atomicMax(&maxes[1], __float_as_uint(rs));
}

__global__ __launch_bounds__(256)
void k_z0(const float* __restrict__ a2, const unsigned* __restrict__ maxes, float* __restrict__ z) {
  __shared__ float s[32][33];
  int h = blockIdx.z;
  int i0 = blockIdx.x * 32, j0 = blockIdx.y * 32;
  float inv = 1.f / (__uint_as_float(maxes[0]) * __uint_as_float(maxes[1]));
  const float* A = a2 + (size_t)h * NCLUST * NCLUST;
  float* Z = z + (size_t)h * NCLUST * NCLUST;
  int t = threadIdx.x;
#pragma unroll
  for (int l = 0; l < 4; ++l) {
    int lin = t + l * 256;
    int a = lin >> 5, b = lin & 31;
    s[a][b] = A[(size_t)(j0 + a) * NCLUST + i0 + b];
  }
  __syncthreads();
#pragma unroll
  for (int l = 0; l < 4; ++l) {
    int lin = t + l * 256;
    int a = lin >> 5, b = lin & 31;
    Z[(size_t)(i0 + a) * NCLUST + j0 + b] = s[b][a] * inv;
  }
}

// ------- batched 512x512 GEMM via split-bf16 MFMA: C = scale*(alpha*A - A@B) -------
__global__ __launch_bounds__(256)
void k_gemm512_mfma(const float* __restrict__ A, const float* __restrict__ B,
                    float* __restrict__ C, float alpha, float scale) {
  __shared__ __align__(16) ushort As_hi[64][40];
  __shared__ __align__(16) ushort As_lo[64][40];
  __shared__ __align__(16) ushort Bs_hi[64][40];
  __shared__ __align__(16) ushort Bs_lo[64][40];
  int h = blockIdx.z;
  const float* Ahp = A + (size_t)h * NCLUST * NCLUST;
  const float* Bhp = B + (size_t)h * NCLUST * NCLUST;
  float* Chp = C + (size_t)h * NCLUST * NCLUST;
  int tid = threadIdx.x;
  int m0 = blockIdx.y * 64, n0 = blockIdx.x * 64;
  int wave = tid >> 6, lane = tid & 63;
  int m_off = (wave >> 1) * 32, n_off = (wave & 1) * 32;
  int lr = lane & 15;
  int ksb = (lane >> 4) * 8;
  int r0a = tid >> 3, kqa = tid & 7;
  int k0b = tid >> 4, nqb = tid & 15;
  f32x4 acc[2][2];
#pragma unroll
  for (int i = 0; i < 2; ++i)
#pragma unroll
    for (int j = 0; j < 2; ++j) acc[i][j] = (f32x4)0.f;

  for (int kk0 = 0; kk0 < NCLUST; kk0 += 32) {
    __syncthreads();
#pragma unroll
    for (int half = 0; half < 2; ++half) {
      int row = r0a + half * 32;
      float4 a4 = *(const float4*)&Ahp[(size_t)(m0 + row) * NCLUST + kk0 + kqa * 4];
      ushort4 hv, lv;
      split2(a4.x, hv.x, lv.x); split2(a4.y, hv.y, lv.y);
      split2(a4.z, hv.z, lv.z); split2(a4.w, hv.w, lv.w);
      *(ushort4*)&As_hi[row][kqa * 4] = hv;
      *(ushort4*)&As_lo[row][kqa * 4] = lv;
    }
#pragma unroll
    for (int half = 0; half < 2; ++half) {
      int krow = k0b + half * 16;
      float4 b4 = *(const float4*)&Bhp[(size_t)(kk0 + krow) * NCLUST + n0 + nqb * 4];
      ushort hx, lx;
      split2(b4.x, hx, lx); Bs_hi[nqb * 4 + 0][krow] = hx; Bs_lo[nqb * 4 + 0][krow] = lx;
      split2(b4.y, hx, lx); Bs_hi[nqb * 4 + 1][krow] = hx; Bs_lo[nqb * 4 + 1][krow] = lx;
      split2(b4.z, hx, lx); Bs_hi[nqb * 4 + 2][krow] = hx; Bs_lo[nqb * 4 + 2][krow] = lx;
      split2(b4.w, hx, lx); Bs_hi[nqb * 4 + 3][krow] = hx; Bs_lo[nqb * 4 + 3][krow] = lx;
    }
    __syncthreads();
    bh8 ahi[2], alo[2], bhi[2], blo[2];
#pragma unroll
    for (int i = 0; i < 2; ++i) {
      ahi[i] = *(const bh8*)&As_hi[m_off + i * 16 + lr][ksb];
      alo[i] = *(const bh8*)&As_lo[m_off + i * 16 + lr][ksb];
    }
#pragma unroll
    for (int j = 0; j < 2; ++j) {
      bhi[j] = *(const bh8*)&Bs_hi[n_off + j * 16 + lr][ksb];
      blo[j] = *(const bh8*)&Bs_lo[n_off + j * 16 + lr][ksb];
    }
#pragma unroll
    for (int i = 0; i < 2; ++i)
#pragma unroll
      for (int j = 0; j < 2; ++j) {
        acc[i][j] = __builtin_amdgcn_mfma_f32_16x16x32_bf16(ahi[i], bhi[j], acc[i][j], 0, 0, 0);
        acc[i][j] = __builtin_amdgcn_mfma_f32_16x16x32_bf16(ahi[i], blo[j], acc[i][j], 0, 0, 0);
        acc[i][j] = __builtin_amdgcn_mfma_f32_16x16x32_bf16(alo[i], bhi[j], acc[i][j], 0, 0, 0);
      }
  }
#pragma unroll
  for (int i = 0; i < 2; ++i)
#pragma unroll
    for (int j = 0; j < 2; ++j)
#pragma unroll
      for (int r = 0; r < 4; ++r) {
        int m = m0 + m_off + i * 16 + (lane >> 4) * 4 + r;
        int n = n0 + n_off + j * 16 + lr;
        float base = (alpha != 0.f) ? alpha * Ahp[(size_t)m * NCLUST + n] : 0.f;
        Chp[(size_t)m * NCLUST + n] = scale * (base - acc[i][j][r]);
      }
}

// -------- t1 partials: softmax(q_l@k^T)@v over one key segment (split-K) --------
__global__ __launch_bounds__(256)
void k_t1_part(const float* __restrict__ ql, const float* __restrict__ k,
               const float* __restrict__ v, float* __restrict__ pacc,
               float* __restrict__ pml) {
  __shared__ float qs[16][68];
  __shared__ float ks[64][68];
  __shared__ float vs[64][68];
  __shared__ float P[16][68];
  __shared__ float red[16][17];
  __shared__ float mrun[16], srun[16], fs[16];
  int h = blockIdx.y;
  int r0 = blockIdx.x * 16;
  int seg = blockIdx.z;
  int t = threadIdx.x;
#pragma unroll
  for (int l = 0; l < 4; ++l) {
    int lin = t + l * 256;
    int r = lin >> 6, d = lin & 63;
    qs[r][d] = ql[(((size_t)h * NCLUST) + r0 + r) * DH + d];
  }
  if (t < 16) { mrun[t] = -1e30f; srun[t] = 0.f; }
  float acc0 = 0, acc1 = 0, acc2 = 0, acc3 = 0;
  int rr = t & 15;
  int jg = t >> 4;
  const float* kh = k + (size_t)h * N_TOK * DH;
  const float* vh = v + (size_t)h * N_TOK * DH;
  __syncthreads();
  for (int j0 = seg * SEGLEN; j0 < (seg + 1) * SEGLEN; j0 += 64) {
#pragma unroll
    for (int l = 0; l < 16; ++l) {
      int lin = t + l * 256;
      int j = lin >> 6, d = lin & 63;
      ks[j][d] = kh[(size_t)(j0 + j) * DH + d];
      vs[j][d] = vh[(size_t)(j0 + j) * DH + d];
    }
    __syncthreads();
    float sv[4];
#pragma unroll
    for (int jj = 0; jj < 4; ++jj) {
      int j = jg * 4 + jj;
      const float4* qv = (const float4*)&qs[rr][0];
      const float4* kv = (const float4*)&ks[j][0];
      float s = 0;
#pragma unroll
      for (int d4 = 0; d4 < 16; ++d4) {
        float4 a = qv[d4], b = kv[d4];
        s += a.x * b.x + a.y * b.y + a.z * b.z + a.w * b.w;
      }
      sv[jj] = s;
    }
    red[rr][jg] = fmaxf(fmaxf(sv[0], sv[1]), fmaxf(sv[2], sv[3]));
    __syncthreads();
    if (t < 16) {
      float cm = red[t][0];
      for (int g = 1; g < 16; ++g) cm = fmaxf(cm, red[t][g]);
      float mo = mrun[t];
      float mn = fmaxf(mo, cm);
      float f = __expf(mo - mn);
      mrun[t] = mn; fs[t] = f; srun[t] *= f;
    }
    __syncthreads();
    float mn = mrun[rr];
    float ls = 0;
#pragma unroll
    for (int jj = 0; jj < 4; ++jj) {
      float e = __expf(sv[jj] - mn);
      P[rr][jg * 4 + jj] = e;
      ls += e;
    }
    red[rr][jg] = ls;
    __syncthreads();
    if (t < 16) {
      float cs = 0;
      for (int g = 0; g < 16; ++g) cs += red[t][g];
      srun[t] += cs;
    }
    float f = fs[rr];
    int dbase = jg * 4;
    float a0 = acc0 * f, a1 = acc1 * f, a2v = acc2 * f, a3v = acc3 * f;
#pragma unroll 8
    for (int j = 0; j < 64; ++j) {
      float p = P[rr][j];
      const float* vrow = &vs[j][dbase];
      a0 += p * vrow[0]; a1 += p * vrow[1]; a2v += p * vrow[2]; a3v += p * vrow[3];
    }
    acc0 = a0; acc1 = a1; acc2 = a2v; acc3 = a3v;
    __syncthreads();
  }
  // unnormalized partial write
  float* pa = &pacc[(((size_t)h * NCLUST + r0 + rr) * SEG + seg) * DH + jg * 4];
  pa[0] = acc0; pa[1] = acc1; pa[2] = acc2; pa[3] = acc3;
  if (t < 16) {
    float2 ml = make_float2(mrun[t], srun[t]);
    *(float2*)&pml[(((size_t)h * NCLUST + r0 + t) * SEG + seg) * 2] = ml;
  }
}

// combine SEG partials -> t1
__global__ void k_t1comb(const float* __restrict__ pacc, const float* __restrict__ pml,
                         float* __restrict__ t1) {
  int r = blockIdx.x, h = blockIdx.y, d = threadIdx.x;  // 64 threads
  size_t base = ((size_t)h * NCLUST + r) * SEG;
  float m[SEG], l[SEG];
  float M = -1e30f;
#pragma unroll
  for (int s = 0; s < SEG; ++s) {
    m[s] = pml[(base + s) * 2];
    l[s] = pml[(base + s) * 2 + 1];
    M = fmaxf(M, m[s]);
  }
  float L = 0.f, o = 0.f;
#pragma unroll
  for (int s = 0; s < SEG; ++s) {
    float w = __expf(m[s] - M);
    L += l[s] * w;
    o += pacc[(base + s) * DH + d] * w;
  }
  t1[((size_t)h * NCLUST + r) * DH + d] = o / L;
}

// ---------------- t2 = z @ t1 ----------------
__global__ void k_t2(const float* __restrict__ z, const float* __restrict__ t1, float* __restrict__ t2) {
  int r = blockIdx.x, h = blockIdx.y, d = threadIdx.x;
  const float* zr = z + (((size_t)h * NCLUST) + r) * NCLUST;
  const float* t1h = t1 + (size_t)h * NCLUST * DH;
  float s = 0;
  for (int c = 0; c < NCLUST; ++c) s += zr[c] * t1h[(size_t)c * DH + d];
  t2[(((size_t)h * NCLUST) + r) * DH + d] = s;
}

// ---------------- out = softmax(q@k_l^T)@t2 + conv33(v) ----------------
__global__ __launch_bounds__(256)
void k_out_attn(const float* __restrict__ q, const float* __restrict__ kl,
                const float* __restrict__ t2, const float* __restrict__ v,
                const float* __restrict__ wres, float* __restrict__ ao) {
  __shared__ float qs[64][68];
  __shared__ float ks[64][68];   // reused as t2-chunk buffer
  __shared__ float Ps[64][68];
  __shared__ float wr[KW];
  int h = blockIdx.y;
  int p0 = blockIdx.x * 64;
  int t = threadIdx.x;
  int ty = t >> 4, tx = t & 15;
  const float* qh  = q  + (size_t)h * N_TOK * DH;
  const float* klh = kl + (size_t)h * NCLUST * DH;
  const float* t2h = t2 + (size_t)h * NCLUST * DH;
  const float* vh  = v  + (size_t)h * N_TOK * DH;
  if (t < KW) wr[t] = wres[h * KW + t];
#pragma unroll
  for (int l = 0; l < 4; ++l) {
    int f4 = t + l * 256;
    int r = f4 >> 4, d4 = f4 & 15;
    *(float4*)&qs[r][d4 * 4] = *(const float4*)&qh[(size_t)(p0 + r) * DH + d4 * 4];
  }
  float m_run[4], s_run[4], accp[4][4];
#pragma unroll
  for (int i = 0; i < 4; ++i) {
    m_run[i] = -1e30f; s_run[i] = 0.f;
#pragma unroll
    for (int j = 0; j < 4; ++j) accp[i][j] = 0.f;
  }
  __syncthreads();

  for (int c0 = 0; c0 < NCLUST; c0 += 64) {
#pragma unroll
    for (int l = 0; l < 4; ++l) {
      int f4 = t + l * 256;
      int r = f4 >> 4, d4 = f4 & 15;
      *(float4*)&ks[r][d4 * 4] = *(const float4*)&klh[(size_t)(c0 + r) * DH + d4 * 4];
    }
    __syncthreads();
    float sc[4][4] = {};
#pragma unroll
    for (int d4 = 0; d4 < 16; ++d4) {
      float4 a[4], b[4];
#pragma unroll
      for (int i = 0; i < 4; ++i) a[i] = *(const float4*)&qs[ty + 16 * i][d4 * 4];
#pragma unroll
      for (int j = 0; j < 4; ++j) b[j] = *(const float4*)&ks[tx + 16 * j][d4 * 4];
#pragma unroll
      for (int i = 0; i < 4; ++i)
#pragma unroll
        for (int j = 0; j < 4; ++j)
          sc[i][j] += a[i].x * b[j].x + a[i].y * b[j].y + a[i].z * b[j].z + a[i].w * b[j].w;
    }
#pragma unroll
    for (int i = 0; i < 4; ++i) {
      float cm = fmaxf(fmaxf(sc[i][0], sc[i][1]), fmaxf(sc[i][2], sc[i][3]));
      cm = fmaxf(cm, __shfl_xor(cm, 1, 16));
      cm = fmaxf(cm, __shfl_xor(cm, 2, 16));
      cm = fmaxf(cm, __shfl_xor(cm, 4, 16));
      cm = fmaxf(cm, __shfl_xor(cm, 8, 16));
      float mo = m_run[i];
      float mn = fmaxf(mo, cm);
      float f = __expf(mo - mn);
      m_run[i] = mn;
      float ls = 0.f;
#pragma unroll
      for (int j = 0; j < 4; ++j) {
        float e = __expf(sc[i][j] - mn);
        Ps[ty + 16 * i][tx + 16 * j] = e;
        ls += e;
      }
      ls += __shfl_xor(ls, 1, 16);
      ls += __shfl_xor(ls, 2, 16);
      ls += __shfl_xor(ls, 4, 16);
      ls += __shfl_xor(ls, 8, 16);
      s_run[i] = s_run[i] * f + ls;
#pragma unroll
      for (int j = 0; j < 4; ++j) accp[i][j] *= f;
    }
    __syncthreads();
#pragma unroll
    for (int l = 0; l < 4; ++l) {
      int f4 = t + l * 256;
      int r = f4 >> 4, d4 = f4 & 15;
      *(float4*)&ks[r][d4 * 4] = *(const float4*)&t2h[(size_t)(c0 + r) * DH + d4 * 4];
    }
    __syncthreads();
#pragma unroll 8
    for (int kk = 0; kk < 64; ++kk) {
      float a[4], b[4];
#pragma unroll
      for (int i = 0; i < 4; ++i) a[i] = Ps[ty + 16 * i][kk];
#pragma unroll
      for (int j = 0; j < 4; ++j) b[j] = ks[kk][tx + 16 * j];
#pragma unroll
      for (int i = 0; i < 4; ++i)
#pragma unroll
        for (int j = 0; j < 4; ++j) accp[i][j] += a[i] * b[j];
    }
    __syncthreads();
  }
#pragma unroll
  for (int i = 0; i < 4; ++i) {
    float inv = 1.f / s_run[i];
#pragma unroll
    for (int j = 0; j < 4; ++j) accp[i][j] *= inv;
  }
#pragma unroll
  for (int i = 0; i < 4; ++i) {
    int prow = p0 + ty + 16 * i;
    for (int tap = 0; tap < KW; ++tap) {
      int srow = prow + tap - KPAD;
      if (srow >= 0 && srow < N_TOK) {
        float w = wr[tap];
        const float* vrow = &vh[(size_t)srow * DH];
#pragma unroll
        for (int j = 0; j < 4; ++j) accp[i][j] += w * vrow[tx + 16 * j];
      }
    }
  }
#pragma unroll
  for (int i = 0; i < 4; ++i) {
    int prow = p0 + ty + 16 * i;
    float* outp = &ao[(size_t)prow * DIMF + h * DH];
#pragma unroll
    for (int j = 0; j < 4; ++j) outp[tx + 16 * j] = accp[i][j];
  }
}

// ---------------- final projection + un-sort scatter ----------------
__global__ __launch_bounds__(256)
void k_proj(const float* __restrict__ ao, const float* __restrict__ wout,
            const float* __restrict__ bout, const int* __restrict__ idx,
            float* __restrict__ out) {
  __shared__ float As[16][65];
  __shared__ float Bs[16][65];
  __shared__ int rowIdx[64];
  int tid = threadIdx.x;
  int p0 = blockIdx.y * 64, j0 = blockIdx.x * 64;
  if (tid < 64) rowIdx[tid] = idx[p0 + tid];
  __syncthreads();
  int ty = tid >> 4, tx = tid & 15;
  float acc[4][4] = {};
  for (int k0 = 0; k0 < DIMF; k0 += 16) {
#pragma unroll
    for (int l = 0; l < 4; ++l) {
      int lin = tid + l * 256;
      int row = lin >> 4, kk = lin & 15;
      As[kk][row] = ao[(size_t)(p0 + row) * DIMF + k0 + kk];
      Bs[kk][row] = wout[(size_t)(j0 + row) * DIMF + k0 + kk];
    }
    __syncthreads();
#pragma unroll
    for (int kk = 0; kk < 16; ++kk) {
      float a[4], b[4];
#pragma unroll
      for (int i = 0; i < 4; ++i) a[i] = As[kk][ty * 4 + i];
#pragma unroll
      for (int j = 0; j < 4; ++j) b[j] = Bs[kk][tx * 4 + j];
#pragma unroll
      for (int i = 0; i < 4; ++i)
#pragma unroll
        for (int j = 0; j < 4; ++j) acc[i][j] += a[i] * b[j];
    }
    __syncthreads();
  }
  float4 bv = *(const float4*)&bout[j0 + tx * 4];
#pragma unroll
  for (int i = 0; i < 4; ++i) {
    int orow = rowIdx[ty * 4 + i];
    float4 o;
    o.x = acc[i][0] + bv.x; o.y = acc[i][1] + bv.y;
    o.z = acc[i][2] + bv.z; o.w = acc[i][3] + bv.w;
    *(float4*)&out[(size_t)orow * DIMF + j0 + tx * 4] = o;
  }
}

extern "C" void kernel_launch(void* const* d_in, const int* in_sizes, int n_in,
                              void* d_out, int out_size, void* d_ws, size_t ws_size,
                              hipStream_t stream) {
  const float* x     = (const float*)d_in[0];
  const int*   labels= (const int*)d_in[1];
  const float* wqkv  = (const float*)d_in[2];
  const float* wres  = (const float*)d_in[3];
  const float* wout  = (const float*)d_in[4];
  const float* bout  = (const float*)d_in[5];
  float* out = (float*)d_out;

  char* base = (char*)d_ws;
  size_t off = 0;
  auto alloc = [&](size_t bytes) -> void* {
    void* p = base + off;
    off = (off + bytes + 255) & ~(size_t)255;
    return p;
  };
  int* idx      = (int*)alloc((size_t)N_TOK * 4);
  int* counts   = (int*)alloc(NCLUST * 4);
  int* offsets  = (int*)alloc(NCLUST * 4);
  unsigned* maxes = (unsigned*)alloc(256);
  size_t qkvBytes = (size_t)HEADS * N_TOK * DH * 4;   // 32 MB each
  float* q    = (float*)alloc(qkvBytes);
  float* kbuf = (float*)alloc(qkvBytes);   // holds K; later pinv temporaries + ao
  float* v    = (float*)alloc(qkvBytes);
  size_t lmBytes = (size_t)HEADS * NCLUST * DH * 4;   // 1 MB each
  float* ql = (float*)alloc(lmBytes);
  float* kl = (float*)alloc(lmBytes);
  float* t1 = (float*)alloc(lmBytes);
  float* t2 = (float*)alloc(lmBytes);     // also pml scratch before k_t2
  size_t matB = (size_t)HEADS * NCLUST * NCLUST * 4;  // 8 MB
  float* a2 = (float*)alloc(matB);
  float* zA = (float*)alloc(matB);
  float* zB = (float*)alloc(matB);        // also pacc scratch before pinv
  // overlays inside kbuf (free after k_t1 partials consumed):
  float* xz  = kbuf;
  float* tm1 = (float*)((char*)kbuf + matB);
  float* tm2 = (float*)((char*)kbuf + 2 * matB);
  float* ao  = kbuf;   // 32 MB, used after pinv

  hipMemsetAsync(counts, 0, NCLUST * 4, stream);
  hipMemsetAsync(maxes, 0, 8, stream);

  k_hist<<<dim3(64), dim3(256), 0, stream>>>(labels, counts);
  k_scan<<<dim3(1), dim3(512), 0, stream>>>(counts, offsets);
  k_build_idx<<<dim3(NCLUST), dim3(64), 0, stream>>>(labels, offsets, idx);
  k_qkv_mfma<<<dim3(QKV_COLS / 64, N_TOK / 64), dim3(256), 0, stream>>>(x, wqkv, idx, q, kbuf, v);
  k_landmarks<<<dim3(NCLUST, HEADS), dim3(64), 0, stream>>>(q, kbuf, offsets, counts, ql, kl);
  k_a2<<<dim3(NCLUST, HEADS), dim3(256), 0, stream>>>(ql, kl, a2);
  k_colrow_max<<<dim3(NCLUST / 64, HEADS), dim3(64), 0, stream>>>(a2, maxes);
  k_z0<<<dim3(16, 16, HEADS), dim3(256), 0, stream>>>(a2, maxes, zA);
  // t1 (split-K partials into zB/t2, combine) before pinv so kbuf/zB reuse is safe
  k_t1_part<<<dim3(NCLUST / 16, HEADS, SEG), dim3(256), 0, stream>>>(ql, kbuf, v, zB, t2);
  k_t1comb<<<dim3(NCLUST, HEADS), dim3(64), 0, stream>>>(zB, t2, t1);

  float* zin = zA;
  float* zout = zB;
  dim3 g8(8, 8, HEADS), b256(256);
  for (int it = 0; it < PINV_IT; ++it) {
    k_gemm512_mfma<<<g8, b256, 0, stream>>>(a2, zin, xz, 0.f, -1.f);       // xz = a2@z
    k_gemm512_mfma<<<g8, b256, 0, stream>>>(xz, xz, tm1, 7.f, 1.f);        // 7xz - xz@xz
    k_gemm512_mfma<<<g8, b256, 0, stream>>>(xz, tm1, tm2, 15.f, 1.f);      // 15xz - xz@tm1
    k_gemm512_mfma<<<g8, b256, 0, stream>>>(zin, tm2, zout, 13.f, 0.25f);  // 0.25*(13z - z@tm2)
    float* tswap = zin; zin = zout; zout = tswap;
  }
  // zin == zA after 6 iterations

  k_t2<<<dim3(NCLUST, HEADS), dim3(64), 0, stream>>>(zin, t1, t2);
  k_out_attn<<<dim3(N_TOK / 64, HEADS), dim3(256), 0, stream>>>(q, kl, t2, v, wres, ao);
  k_proj<<<dim3(DIMF / 64, N_TOK / 64), dim3(256), 0, stream>>>(ao, wout, bout, idx, out);
}